// Round 13
// baseline (376.876 us; speedup 1.0000x reference)
//
#include <hip/hip_runtime.h>

#define IN_F 32
#define OUT_F 32
#define EDGE_F 16
#define BN_EPS 1e-5f
#define SLOPE 0.01f

typedef _Float16 half_t;
typedef __attribute__((ext_vector_type(4))) _Float16 h4;
typedef __attribute__((ext_vector_type(8))) _Float16 f16x8;
typedef __attribute__((ext_vector_type(4))) float f32x4;

#define BCOLS 544        // [W: f*32+o (512) | xb: 512+o (32)]
#define YSTRIDE 552      // fp16 elems per LDS Y row

// ---------------- P0: build Bt fp16; zero cnt_s + stats ----------------
__global__ __launch_bounds__(256) void prep_bt_kernel(
    const float* __restrict__ W, const float* __restrict__ b,
    half_t* __restrict__ BtG, int* __restrict__ cnt_s,
    float* __restrict__ stats, int NB) {
  int idx = blockIdx.x * 256 + threadIdx.x;
  if (idx < NB) cnt_s[idx] = 0;
  if (idx < 64) stats[idx] = 0.f;
  if (idx >= BCOLS * 32) return;
  int o = idx & 31;
  int k = (idx >> 5) & 31;
  int fp = idx >> 10;  // 0..16
  float v;
  int col;
  if (fp < 16) { v = W[(size_t)fp * 1024 + k * 32 + o]; col = fp * 32 + o; }
  else         { v = b[k * 32 + o];                     col = 512 + o; }
  BtG[(size_t)col * 32 + k] = (half_t)v;
}

// ---------------- S1: histograms: src>>5 buckets, dst per-node ----------------
__global__ __launch_bounds__(256) void hist2_kernel(
    const int* __restrict__ ei, int* __restrict__ cnt_s,
    int* __restrict__ cnt_d, int E) {
  int e = blockIdx.x * 256 + threadIdx.x;
  if (e < E) {
    atomicAdd(&cnt_s[ei[e] >> 5], 1);
    atomicAdd(&cnt_d[ei[E + e]], 1);
  }
}

// ---------------- S2a: single-block scan over NB src buckets ----------------
__global__ __launch_bounds__(1024) void scan_s_kernel(
    const int* __restrict__ cnt, int* __restrict__ rp,
    int* __restrict__ cur, int NB, int E) {
  __shared__ int lds[1024];
  int t = threadIdx.x;
  int C = (NB + 1023) >> 10;
  int base = t * C;
  int s = 0;
  for (int c = 0; c < C; ++c) { int i = base + c; if (i < NB) s += cnt[i]; }
  lds[t] = s;
  __syncthreads();
  for (int off = 1; off < 1024; off <<= 1) {
    int u = (t >= off) ? lds[t - off] : 0;
    __syncthreads();
    lds[t] += u;
    __syncthreads();
  }
  int running = lds[t] - s;
  for (int c = 0; c < C; ++c) {
    int i = base + c;
    if (i < NB) { rp[i] = running; cur[i] = running; running += cnt[i]; }
  }
  if (t == 0) rp[NB] = E;
}

// ---------------- S2b: per-node dst scan (3 levels) ----------------
__global__ __launch_bounds__(256) void scan_a_kernel(
    const int* __restrict__ cnt, int* __restrict__ rp, int* __restrict__ bsum, int N) {
  __shared__ int lds[256];
  int i = blockIdx.x * 256 + threadIdx.x;
  int v = (i < N) ? cnt[i] : 0;
  lds[threadIdx.x] = v;
  __syncthreads();
  int ex = 0;
  for (int j = 0; j < threadIdx.x; ++j) ex += lds[j];
  if (i < N) rp[i] = ex;
  if (threadIdx.x == 255) bsum[blockIdx.x] = ex + v;
}

__global__ __launch_bounds__(512) void scan_b_kernel(
    const int* __restrict__ bsum, int* __restrict__ bcur, int nb) {
  __shared__ int lds[512];
  int t = threadIdx.x;
  lds[t] = (t < nb) ? bsum[t] : 0;
  __syncthreads();
  int ex = 0;
  for (int j = 0; j < t; ++j) ex += lds[j];
  if (t < nb) bcur[t] = ex;
}

__global__ __launch_bounds__(256) void scan_c_kernel(
    int* __restrict__ rp, int* __restrict__ cursor,
    const int* __restrict__ bcur, int N, int E) {
  int i = blockIdx.x * 256 + threadIdx.x;
  if (i < N) {
    int v = rp[i] + bcur[i >> 8];
    rp[i] = v;
    cursor[i] = v;
  }
  if (i == 0) rp[N] = E;
}

// ---------------- S3: dual ranked scatter ----------------
__global__ __launch_bounds__(256) void scatter2_kernel(
    const int* __restrict__ ei, int* __restrict__ cur_s, int* __restrict__ cur_d,
    int* __restrict__ perm_s, int* __restrict__ perm_d, int E) {
  int e = blockIdx.x * 256 + threadIdx.x;
  if (e < E) {
    int s = ei[e], d = ei[E + e];
    int rs = atomicAdd(&cur_s[s >> 5], 1);
    perm_s[rs] = (e << 5) | (s & 31);
    int rd = atomicAdd(&cur_d[d], 1);
    perm_d[rd] = rs;
  }
}

// ---------------- PASS 1: per-32-src-node tile: MFMA Y -> LDS, edges -> coalesced fp16 msg ----------------
__global__ __launch_bounds__(256, 4) void fused1_kernel(
    const float* __restrict__ x, const half_t* __restrict__ BtG,
    const float* __restrict__ ef, const int* __restrict__ perm_s,
    const int* __restrict__ rp_s, half_t* __restrict__ msg, int N) {
  __shared__ half_t Yl[32][YSTRIDE];  // 35.3 KB

  int b = blockIdx.x;
  int n0 = b * 32;
  int t = threadIdx.x;

  int wv = t >> 6, lane = t & 63, lr = lane & 15, kg = lane >> 4;
  int nh = wv & 1, ch = wv >> 1;
  int row = n0 + nh * 16 + lr;

  f16x8 a = (f16x8)(half_t)0.f;
  if (row < N) {
    float4 u0 = *(const float4*)(x + (size_t)row * 32 + kg * 8);
    float4 u1 = *(const float4*)(x + (size_t)row * 32 + kg * 8 + 4);
    a[0] = (half_t)u0.x; a[1] = (half_t)u0.y; a[2] = (half_t)u0.z; a[3] = (half_t)u0.w;
    a[4] = (half_t)u1.x; a[5] = (half_t)u1.y; a[6] = (half_t)u1.z; a[7] = (half_t)u1.w;
  }

  int nl0 = nh * 16 + kg * 4;
  for (int ci = 0; ci < 17; ++ci) {
    int col = (ch * 17 + ci) * 16 + lr;  // 0..543
    f16x8 bf = *(const f16x8*)(BtG + (size_t)col * 32 + kg * 8);
    f32x4 c = {0.f, 0.f, 0.f, 0.f};
    c = __builtin_amdgcn_mfma_f32_16x16x32_f16(a, bf, c, 0, 0, 0);
    Yl[nl0 + 0][col] = (half_t)c[0];
    Yl[nl0 + 1][col] = (half_t)c[1];
    Yl[nl0 + 2][col] = (half_t)c[2];
    Yl[nl0 + 3][col] = (half_t)c[3];
  }
  __syncthreads();

  int grp = t >> 3, oq = t & 7;
  int kb = rp_s[b], ke = rp_s[b + 1];
  for (int k = kb + grp; k < ke; k += 32) {
    int pk = perm_s[k];
    int e = pk >> 5, sl = pk & 31;

    const float4* ep4 = (const float4*)(ef + (size_t)e * EDGE_F);
    float4 f0 = ep4[0], f1 = ep4[1], f2 = ep4[2], f3 = ep4[3];
    float efr[16] = {f0.x, f0.y, f0.z, f0.w, f1.x, f1.y, f1.z, f1.w,
                     f2.x, f2.y, f2.z, f2.w, f3.x, f3.y, f3.z, f3.w};

    float acc[4];
    {
      h4 xb = *(const h4*)(&Yl[sl][512 + oq * 4]);
      acc[0] = (float)xb[0]; acc[1] = (float)xb[1];
      acc[2] = (float)xb[2]; acc[3] = (float)xb[3];
    }
#pragma unroll
    for (int f = 0; f < 16; ++f) {
      h4 yv = *(const h4*)(&Yl[sl][f * 32 + oq * 4]);
      acc[0] = fmaf(efr[f], (float)yv[0], acc[0]);
      acc[1] = fmaf(efr[f], (float)yv[1], acc[1]);
      acc[2] = fmaf(efr[f], (float)yv[2], acc[2]);
      acc[3] = fmaf(efr[f], (float)yv[3], acc[3]);
    }

    h4 hv;
    hv[0] = (half_t)acc[0]; hv[1] = (half_t)acc[1];
    hv[2] = (half_t)acc[2]; hv[3] = (half_t)acc[3];
    *(h4*)(msg + (size_t)k * 32 + oq * 4) = hv;
  }
}

// ---------------- PASS 2: per-node register aggregation + x@root + bias; BN partials -> private slot ----------------
__global__ __launch_bounds__(256) void agg2_kernel(
    const half_t* __restrict__ msg, const int* __restrict__ perm_d,
    const int* __restrict__ rp, const float* __restrict__ x,
    const float* __restrict__ root, const float* __restrict__ bias,
    float* __restrict__ out, float* __restrict__ partials, int N) {
  __shared__ float rl[1024];
  __shared__ float bl[32];
  __shared__ float ps[256][4];
  __shared__ float pq[256][4];

  int t = threadIdx.x;
  for (int i = t; i < 1024; i += 256) rl[i] = root[i];
  if (t < 32) bl[t] = bias[t];
  __syncthreads();

  int grp = t >> 3, oq = t & 7;
  int n = blockIdx.x * 32 + grp;
  float hv[4] = {0.f, 0.f, 0.f, 0.f};

  if (n < N) {
    int kb = rp[n], ke = rp[n + 1];
    for (int k = kb; k < ke; ++k) {
      int rs = perm_d[k];
      h4 v = *(const h4*)(msg + (size_t)rs * 32 + oq * 4);
      hv[0] += (float)v[0]; hv[1] += (float)v[1];
      hv[2] += (float)v[2]; hv[3] += (float)v[3];
    }
    int c0 = oq * 4;
#pragma unroll
    for (int j = 0; j < 4; ++j) hv[j] += bl[c0 + j];
    const float4* xr = (const float4*)(x + (size_t)n * 32);
#pragma unroll
    for (int q = 0; q < 8; ++q) {
      float4 xv = xr[q];
#pragma unroll
      for (int j = 0; j < 4; ++j) {
        hv[j] = fmaf(xv.x, rl[(q * 4 + 0) * 32 + c0 + j], hv[j]);
        hv[j] = fmaf(xv.y, rl[(q * 4 + 1) * 32 + c0 + j], hv[j]);
        hv[j] = fmaf(xv.z, rl[(q * 4 + 2) * 32 + c0 + j], hv[j]);
        hv[j] = fmaf(xv.w, rl[(q * 4 + 3) * 32 + c0 + j], hv[j]);
      }
    }
    *(float4*)(out + (size_t)n * 32 + c0) = make_float4(hv[0], hv[1], hv[2], hv[3]);
  }

  // BN partials: LDS tree then PRIVATE per-block slot (plain stores, no contention)
#pragma unroll
  for (int j = 0; j < 4; ++j) {
    ps[t][j] = (n < N) ? hv[j] : 0.f;
    pq[t][j] = (n < N) ? hv[j] * hv[j] : 0.f;
  }
  __syncthreads();
  if (t < 32) {
    float s = 0.f, s2 = 0.f;
    int lo = t >> 2, j = t & 3;
    for (int g = 0; g < 32; ++g) { s += ps[g * 8 + lo][j]; s2 += pq[g * 8 + lo][j]; }
    float* slot = partials + (size_t)blockIdx.x * 64;
    slot[t] = s;
    slot[32 + t] = s2;
  }
}

// ---------------- stats reduce: stats[c] = sum_g partials[g*64+c] ----------------
__global__ __launch_bounds__(256) void stats_reduce_kernel(
    const float* __restrict__ partials, float* __restrict__ stats, int G) {
  __shared__ float acc[4][64];
  int t = threadIdx.x;
  int c = t & 63, q = t >> 6;
  float s = 0.f;
  for (int g = q; g < G; g += 4) s += partials[(size_t)g * 64 + c];
  acc[q][c] = s;
  __syncthreads();
  if (t < 64) stats[t] = acc[0][t] + acc[1][t] + acc[2][t] + acc[3][t];
}

// ---------------- K4: normalize + affine + LeakyReLU ----------------
__global__ __launch_bounds__(256) void bn_apply_kernel(
    float* __restrict__ h, const float* __restrict__ stats,
    const float* __restrict__ gamma, const float* __restrict__ beta,
    int total, float invN) {
  int t = blockIdx.x * blockDim.x + threadIdx.x;
  int i4 = t * 4;
  if (i4 >= total) return;
  float4 v = *(const float4*)(h + i4);
  float r[4] = {v.x, v.y, v.z, v.w};
  int o0 = i4 & 31;
#pragma unroll
  for (int j = 0; j < 4; ++j) {
    int o = o0 + j;
    float m = stats[o] * invN;
    float var = fmaf(-m, m, stats[32 + o] * invN);
    float sc = rsqrtf(var + BN_EPS) * gamma[o];
    float val = (r[j] - m) * sc + beta[o];
    r[j] = val >= 0.f ? val : SLOPE * val;
  }
  *(float4*)(h + i4) = make_float4(r[0], r[1], r[2], r[3]);
}

// ---------------- Fallback path (tiny ws) ----------------
__global__ __launch_bounds__(256) void node_root_kernel(
    const float* __restrict__ x, const float* __restrict__ root,
    const float* __restrict__ bias, float* __restrict__ agg, int N) {
  __shared__ float rl[IN_F * OUT_F];
  __shared__ float bl[OUT_F];
  for (int t = threadIdx.x; t < IN_F * OUT_F; t += blockDim.x) rl[t] = root[t];
  if (threadIdx.x < OUT_F) bl[threadIdx.x] = bias[threadIdx.x];
  __syncthreads();
  int n = blockIdx.x * blockDim.x + threadIdx.x;
  bool valid = (n < N);
  int nu = valid ? n : 0;
  float xr[IN_F];
  const float4* xp = (const float4*)(x + (size_t)nu * IN_F);
#pragma unroll
  for (int q = 0; q < IN_F / 4; ++q) {
    float4 v = xp[q];
    xr[q * 4 + 0] = v.x; xr[q * 4 + 1] = v.y; xr[q * 4 + 2] = v.z; xr[q * 4 + 3] = v.w;
  }
  float acc[OUT_F];
#pragma unroll
  for (int o = 0; o < OUT_F; ++o) acc[o] = bl[o];
#pragma unroll
  for (int i = 0; i < IN_F; ++i) {
    float xi = xr[i];
#pragma unroll
    for (int o = 0; o < OUT_F; ++o) acc[o] = fmaf(xi, rl[i * OUT_F + o], acc[o]);
  }
  if (valid) {
    float4* op = (float4*)(agg + (size_t)n * OUT_F);
#pragma unroll
    for (int q = 0; q < OUT_F / 4; ++q)
      op[q] = make_float4(acc[q * 4 + 0], acc[q * 4 + 1], acc[q * 4 + 2], acc[q * 4 + 3]);
  }
}

__global__ __launch_bounds__(256) void edge_kernel(
    const float* __restrict__ x, const float* __restrict__ ef,
    const float* __restrict__ W, const float* __restrict__ b,
    const int* __restrict__ ei, float* __restrict__ agg, int E) {
  __shared__ float Wl[EDGE_F * IN_F * OUT_F];
  int e = blockIdx.x * blockDim.x + threadIdx.x;
  bool valid = (e < E);
  int eu = valid ? e : 0;
  int s = ei[eu];
  int d = ei[E + eu];
  float efr[EDGE_F];
  {
    const float4* ep = (const float4*)(ef + (size_t)eu * EDGE_F);
#pragma unroll
    for (int q = 0; q < EDGE_F / 4; ++q) {
      float4 v = ep[q];
      efr[q * 4 + 0] = v.x; efr[q * 4 + 1] = v.y;
      efr[q * 4 + 2] = v.z; efr[q * 4 + 3] = v.w;
    }
  }
  const float* xrow = x + (size_t)s * IN_F;
  float acc[OUT_F];
#pragma unroll
  for (int o = 0; o < OUT_F; ++o) acc[o] = 0.f;
  for (int t = threadIdx.x; t < IN_F * OUT_F; t += 256) Wl[t] = b[t];
  __syncthreads();
  for (int i = 0; i < IN_F; ++i) {
    float xi = xrow[i];
    const float* br = &Wl[i * OUT_F];
#pragma unroll
    for (int o = 0; o < OUT_F; ++o) acc[o] = fmaf(xi, br[o], acc[o]);
  }
  __syncthreads();
  for (int t = threadIdx.x; t < EDGE_F * IN_F * OUT_F / 4; t += 256)
    ((float4*)Wl)[t] = ((const float4*)W)[t];
  __syncthreads();
  for (int i = 0; i < IN_F; ++i) {
    float xi = xrow[i];
#pragma unroll
    for (int f = 0; f < EDGE_F; ++f) {
      float m = efr[f] * xi;
      const float* wr = &Wl[(f * IN_F + i) * OUT_F];
#pragma unroll
      for (int o = 0; o < OUT_F; ++o) acc[o] = fmaf(m, wr[o], acc[o]);
    }
  }
  if (valid) {
    float* dp = agg + (size_t)d * OUT_F;
#pragma unroll
    for (int o = 0; o < OUT_F; ++o) atomicAdd(dp + o, acc[o]);
  }
}

__global__ __launch_bounds__(256) void bn_stats_kernel(
    const float* __restrict__ h, float* __restrict__ stats, int total) {
  int t = blockIdx.x * blockDim.x + threadIdx.x;
  int stride = gridDim.x * blockDim.x;
  float s = 0.f, s2 = 0.f;
  for (int idx = t; idx < total; idx += stride) {
    float v = h[idx];
    s += v;
    s2 = fmaf(v, v, s2);
  }
  __shared__ float ls[256], ls2[256];
  ls[threadIdx.x] = s;
  ls2[threadIdx.x] = s2;
  __syncthreads();
  if (threadIdx.x < 32) {
    float a = ls[threadIdx.x], a2 = ls2[threadIdx.x];
    for (int j = 32 + threadIdx.x; j < 256; j += 32) { a += ls[j]; a2 += ls2[j]; }
    atomicAdd(&stats[threadIdx.x], a);
    atomicAdd(&stats[32 + threadIdx.x], a2);
  }
}

extern "C" void kernel_launch(void* const* d_in, const int* in_sizes, int n_in,
                              void* d_out, int out_size, void* d_ws, size_t ws_size,
                              hipStream_t stream) {
  const float* x     = (const float*)d_in[0];
  const float* ef    = (const float*)d_in[1];
  const float* W     = (const float*)d_in[2];
  const float* b     = (const float*)d_in[3];
  const float* root  = (const float*)d_in[4];
  const float* bias  = (const float*)d_in[5];
  const float* gamma = (const float*)d_in[6];
  const float* beta  = (const float*)d_in[7];
  const int*   ei    = (const int*)d_in[8];

  int N = in_sizes[0] / IN_F;
  int E = in_sizes[1] / EDGE_F;
  int total = N * OUT_F;
  int NB = (N + 31) / 32;
  int nb = (N + 255) / 256;

  float* out = (float*)d_out;
  char* wsb = (char*)d_ws;

  size_t off = 0;
  auto alloc = [&](size_t bytes) { size_t o = off; off = (off + bytes + 255) & ~(size_t)255; return o; };
  float*  stats    = (float*)(wsb + alloc(256));
  half_t* BtG      = (half_t*)(wsb + alloc((size_t)BCOLS * 32 * sizeof(half_t)));
  int*    cnt_s    = (int*)(wsb + alloc((size_t)NB * 4));
  int*    rp_s     = (int*)(wsb + alloc((size_t)(NB + 1) * 4));
  int*    cur_s    = (int*)(wsb + alloc((size_t)NB * 4));
  int*    cnt_d    = (int*)(wsb + alloc((size_t)N * 4));
  int*    rp_d     = (int*)(wsb + alloc((size_t)(N + 1) * 4));
  int*    cur_d    = (int*)(wsb + alloc((size_t)N * 4));
  int*    bsum     = (int*)(wsb + alloc((size_t)nb * 4));
  int*    bcur     = (int*)(wsb + alloc((size_t)nb * 4));
  int*    perm_s   = (int*)(wsb + alloc((size_t)E * 4));
  int*    perm_d   = (int*)(wsb + alloc((size_t)E * 4));
  float*  partials = (float*)(wsb + alloc((size_t)NB * 64 * sizeof(float)));
  half_t* msg      = (half_t*)(wsb + alloc((size_t)E * 32 * sizeof(half_t)));
  size_t need = off;

  bool fits = ((size_t)E << 5) < 0x7FFFFFFF;

  if (ws_size >= need && fits && nb <= 512) {
    int pgrid = (BCOLS * 32 + 255) / 256;
    int ngrid = (NB + 255) / 256;
    if (ngrid > pgrid) pgrid = ngrid;
    hipMemsetAsync(cnt_d, 0, (size_t)N * 4, stream);
    prep_bt_kernel<<<pgrid, 256, 0, stream>>>(W, b, BtG, cnt_s, stats, NB);
    hist2_kernel<<<(E + 255) / 256, 256, 0, stream>>>(ei, cnt_s, cnt_d, E);
    scan_s_kernel<<<1, 1024, 0, stream>>>(cnt_s, rp_s, cur_s, NB, E);
    scan_a_kernel<<<nb, 256, 0, stream>>>(cnt_d, rp_d, bsum, N);
    scan_b_kernel<<<1, 512, 0, stream>>>(bsum, bcur, nb);
    scan_c_kernel<<<nb, 256, 0, stream>>>(rp_d, cur_d, bcur, N, E);
    scatter2_kernel<<<(E + 255) / 256, 256, 0, stream>>>(ei, cur_s, cur_d, perm_s, perm_d, E);
    fused1_kernel<<<NB, 256, 0, stream>>>(x, BtG, ef, perm_s, rp_s, msg, N);
    agg2_kernel<<<NB, 256, 0, stream>>>(msg, perm_d, rp_d, x, root, bias, out, partials, N);
    stats_reduce_kernel<<<1, 256, 0, stream>>>(partials, stats, NB);
  } else {
    hipMemsetAsync(stats, 0, 256, stream);
    node_root_kernel<<<(N + 255) / 256, 256, 0, stream>>>(x, root, bias, out, N);
    edge_kernel<<<(E + 255) / 256, 256, 0, stream>>>(x, ef, W, b, ei, out, E);
    bn_stats_kernel<<<1024, 256, 0, stream>>>(out, stats, total);
  }
  bn_apply_kernel<<<(total / 4 + 255) / 256, 256, 0, stream>>>(out, stats, gamma, beta, total, 1.0f / (float)N);
}

// Round 14
// 198.959 us; speedup vs baseline: 1.8942x; 1.8942x over previous
//
#include <hip/hip_runtime.h>

#define IN_F 32
#define OUT_F 32
#define EDGE_F 16
#define BN_EPS 1e-5f
#define SLOPE 0.01f

typedef _Float16 half_t;
typedef __attribute__((ext_vector_type(4))) _Float16 h4;
typedef __attribute__((ext_vector_type(8))) _Float16 f16x8;
typedef __attribute__((ext_vector_type(4))) float f32x4;

#define BCOLS 544        // [W: f*32+o (512) | xb: 512+o (32)]
#define YSTRIDE 552      // fp16 elems per LDS Y row

// ---------------- P0: build Bt fp16; zero cnt_s + stats ----------------
__global__ __launch_bounds__(256) void prep_bt_kernel(
    const float* __restrict__ W, const float* __restrict__ b,
    half_t* __restrict__ BtG, int* __restrict__ cnt_s,
    float* __restrict__ stats, int NB) {
  int idx = blockIdx.x * 256 + threadIdx.x;
  if (idx < NB) cnt_s[idx] = 0;
  if (idx < 64) stats[idx] = 0.f;
  if (idx >= BCOLS * 32) return;
  int o = idx & 31;
  int k = (idx >> 5) & 31;
  int fp = idx >> 10;  // 0..16
  float v;
  int col;
  if (fp < 16) { v = W[(size_t)fp * 1024 + k * 32 + o]; col = fp * 32 + o; }
  else         { v = b[k * 32 + o];                     col = 512 + o; }
  BtG[(size_t)col * 32 + k] = (half_t)v;
}

// ---------------- S1: histograms: src>>5 buckets, dst per-node ----------------
__global__ __launch_bounds__(256) void hist2_kernel(
    const int* __restrict__ ei, int* __restrict__ cnt_s,
    int* __restrict__ cnt_d, int E) {
  int e = blockIdx.x * 256 + threadIdx.x;
  if (e < E) {
    atomicAdd(&cnt_s[ei[e] >> 5], 1);
    atomicAdd(&cnt_d[ei[E + e]], 1);
  }
}

// ---------------- S2a: single-block scan over NB src buckets ----------------
__global__ __launch_bounds__(1024) void scan_s_kernel(
    const int* __restrict__ cnt, int* __restrict__ rp,
    int* __restrict__ cur, int NB, int E) {
  __shared__ int lds[1024];
  int t = threadIdx.x;
  int C = (NB + 1023) >> 10;
  int base = t * C;
  int s = 0;
  for (int c = 0; c < C; ++c) { int i = base + c; if (i < NB) s += cnt[i]; }
  lds[t] = s;
  __syncthreads();
  for (int off = 1; off < 1024; off <<= 1) {
    int u = (t >= off) ? lds[t - off] : 0;
    __syncthreads();
    lds[t] += u;
    __syncthreads();
  }
  int running = lds[t] - s;
  for (int c = 0; c < C; ++c) {
    int i = base + c;
    if (i < NB) { rp[i] = running; cur[i] = running; running += cnt[i]; }
  }
  if (t == 0) rp[NB] = E;
}

// ---------------- S2b: per-node dst scan (3 levels) ----------------
__global__ __launch_bounds__(256) void scan_a_kernel(
    const int* __restrict__ cnt, int* __restrict__ rp, int* __restrict__ bsum, int N) {
  __shared__ int lds[256];
  int i = blockIdx.x * 256 + threadIdx.x;
  int v = (i < N) ? cnt[i] : 0;
  lds[threadIdx.x] = v;
  __syncthreads();
  int ex = 0;
  for (int j = 0; j < threadIdx.x; ++j) ex += lds[j];
  if (i < N) rp[i] = ex;
  if (threadIdx.x == 255) bsum[blockIdx.x] = ex + v;
}

__global__ __launch_bounds__(512) void scan_b_kernel(
    const int* __restrict__ bsum, int* __restrict__ bcur, int nb) {
  __shared__ int lds[512];
  int t = threadIdx.x;
  lds[t] = (t < nb) ? bsum[t] : 0;
  __syncthreads();
  int ex = 0;
  for (int j = 0; j < t; ++j) ex += lds[j];
  if (t < nb) bcur[t] = ex;
}

__global__ __launch_bounds__(256) void scan_c_kernel(
    int* __restrict__ rp, int* __restrict__ cursor,
    const int* __restrict__ bcur, int N, int E) {
  int i = blockIdx.x * 256 + threadIdx.x;
  if (i < N) {
    int v = rp[i] + bcur[i >> 8];
    rp[i] = v;
    cursor[i] = v;
  }
  if (i == 0) rp[N] = E;
}

// ---------------- S3: dual ranked scatter ----------------
__global__ __launch_bounds__(256) void scatter2_kernel(
    const int* __restrict__ ei, int* __restrict__ cur_s, int* __restrict__ cur_d,
    int* __restrict__ perm_s, int* __restrict__ perm_d, int E) {
  int e = blockIdx.x * 256 + threadIdx.x;
  if (e < E) {
    int s = ei[e], d = ei[E + e];
    int rs = atomicAdd(&cur_s[s >> 5], 1);
    perm_s[rs] = (e << 5) | (s & 31);
    int rd = atomicAdd(&cur_d[d], 1);
    perm_d[rd] = rs;
  }
}

// ---------------- PASS 1: per-32-src-node tile: MFMA Y -> LDS, edges -> coalesced fp16 msg ----------------
__global__ __launch_bounds__(256, 4) void fused1_kernel(
    const float* __restrict__ x, const half_t* __restrict__ BtG,
    const float* __restrict__ ef, const int* __restrict__ perm_s,
    const int* __restrict__ rp_s, half_t* __restrict__ msg, int N) {
  __shared__ half_t Yl[32][YSTRIDE];  // 35.3 KB

  int b = blockIdx.x;
  int n0 = b * 32;
  int t = threadIdx.x;

  int wv = t >> 6, lane = t & 63, lr = lane & 15, kg = lane >> 4;
  int nh = wv & 1, ch = wv >> 1;
  int row = n0 + nh * 16 + lr;

  f16x8 a = (f16x8)(half_t)0.f;
  if (row < N) {
    float4 u0 = *(const float4*)(x + (size_t)row * 32 + kg * 8);
    float4 u1 = *(const float4*)(x + (size_t)row * 32 + kg * 8 + 4);
    a[0] = (half_t)u0.x; a[1] = (half_t)u0.y; a[2] = (half_t)u0.z; a[3] = (half_t)u0.w;
    a[4] = (half_t)u1.x; a[5] = (half_t)u1.y; a[6] = (half_t)u1.z; a[7] = (half_t)u1.w;
  }

  int nl0 = nh * 16 + kg * 4;
  for (int ci = 0; ci < 17; ++ci) {
    int col = (ch * 17 + ci) * 16 + lr;  // 0..543
    f16x8 bf = *(const f16x8*)(BtG + (size_t)col * 32 + kg * 8);
    f32x4 c = {0.f, 0.f, 0.f, 0.f};
    c = __builtin_amdgcn_mfma_f32_16x16x32_f16(a, bf, c, 0, 0, 0);
    Yl[nl0 + 0][col] = (half_t)c[0];
    Yl[nl0 + 1][col] = (half_t)c[1];
    Yl[nl0 + 2][col] = (half_t)c[2];
    Yl[nl0 + 3][col] = (half_t)c[3];
  }
  __syncthreads();

  int grp = t >> 3, oq = t & 7;
  int kb = rp_s[b], ke = rp_s[b + 1];
  for (int k = kb + grp; k < ke; k += 32) {
    int pk = perm_s[k];
    int e = pk >> 5, sl = pk & 31;

    const float4* ep4 = (const float4*)(ef + (size_t)e * EDGE_F);
    float4 f0 = ep4[0], f1 = ep4[1], f2 = ep4[2], f3 = ep4[3];
    float efr[16] = {f0.x, f0.y, f0.z, f0.w, f1.x, f1.y, f1.z, f1.w,
                     f2.x, f2.y, f2.z, f2.w, f3.x, f3.y, f3.z, f3.w};

    float acc[4];
    {
      h4 xb = *(const h4*)(&Yl[sl][512 + oq * 4]);
      acc[0] = (float)xb[0]; acc[1] = (float)xb[1];
      acc[2] = (float)xb[2]; acc[3] = (float)xb[3];
    }
#pragma unroll
    for (int f = 0; f < 16; ++f) {
      h4 yv = *(const h4*)(&Yl[sl][f * 32 + oq * 4]);
      acc[0] = fmaf(efr[f], (float)yv[0], acc[0]);
      acc[1] = fmaf(efr[f], (float)yv[1], acc[1]);
      acc[2] = fmaf(efr[f], (float)yv[2], acc[2]);
      acc[3] = fmaf(efr[f], (float)yv[3], acc[3]);
    }

    h4 hv;
    hv[0] = (half_t)acc[0]; hv[1] = (half_t)acc[1];
    hv[2] = (half_t)acc[2]; hv[3] = (half_t)acc[3];
    *(h4*)(msg + (size_t)k * 32 + oq * 4) = hv;
  }
}

// ---------------- PASS 2: per-node register aggregation + x@root + bias; BN partials -> private slot ----------------
__global__ __launch_bounds__(256) void agg2_kernel(
    const half_t* __restrict__ msg, const int* __restrict__ perm_d,
    const int* __restrict__ rp, const float* __restrict__ x,
    const float* __restrict__ root, const float* __restrict__ bias,
    float* __restrict__ out, float* __restrict__ partials, int N) {
  __shared__ float rl[1024];
  __shared__ float bl[32];
  __shared__ float ps[256][4];
  __shared__ float pq[256][4];

  int t = threadIdx.x;
  for (int i = t; i < 1024; i += 256) rl[i] = root[i];
  if (t < 32) bl[t] = bias[t];
  __syncthreads();

  int grp = t >> 3, oq = t & 7;
  int n = blockIdx.x * 32 + grp;
  float hv[4] = {0.f, 0.f, 0.f, 0.f};

  if (n < N) {
    int kb = rp[n], ke = rp[n + 1];
    for (int k = kb; k < ke; ++k) {
      int rs = perm_d[k];
      h4 v = *(const h4*)(msg + (size_t)rs * 32 + oq * 4);
      hv[0] += (float)v[0]; hv[1] += (float)v[1];
      hv[2] += (float)v[2]; hv[3] += (float)v[3];
    }
    int c0 = oq * 4;
#pragma unroll
    for (int j = 0; j < 4; ++j) hv[j] += bl[c0 + j];
    const float4* xr = (const float4*)(x + (size_t)n * 32);
#pragma unroll
    for (int q = 0; q < 8; ++q) {
      float4 xv = xr[q];
#pragma unroll
      for (int j = 0; j < 4; ++j) {
        hv[j] = fmaf(xv.x, rl[(q * 4 + 0) * 32 + c0 + j], hv[j]);
        hv[j] = fmaf(xv.y, rl[(q * 4 + 1) * 32 + c0 + j], hv[j]);
        hv[j] = fmaf(xv.z, rl[(q * 4 + 2) * 32 + c0 + j], hv[j]);
        hv[j] = fmaf(xv.w, rl[(q * 4 + 3) * 32 + c0 + j], hv[j]);
      }
    }
    *(float4*)(out + (size_t)n * 32 + c0) = make_float4(hv[0], hv[1], hv[2], hv[3]);
  }

  // BN partials: LDS tree then PRIVATE per-block slot (plain stores, no contention)
#pragma unroll
  for (int j = 0; j < 4; ++j) {
    ps[t][j] = (n < N) ? hv[j] : 0.f;
    pq[t][j] = (n < N) ? hv[j] * hv[j] : 0.f;
  }
  __syncthreads();
  if (t < 32) {
    float s = 0.f, s2 = 0.f;
    int lo = t >> 2, j = t & 3;
    for (int g = 0; g < 32; ++g) { s += ps[g * 8 + lo][j]; s2 += pq[g * 8 + lo][j]; }
    float* slot = partials + (size_t)blockIdx.x * 64;
    slot[t] = s;
    slot[32 + t] = s2;
  }
}

// ---------------- stats reduce: PARALLEL (64 blocks), few atomics per column ----------------
__global__ __launch_bounds__(256) void stats_reduce_kernel(
    const float* __restrict__ partials, float* __restrict__ stats, int G) {
  __shared__ float acc[4][64];
  int t = threadIdx.x;
  int c = t & 63, q = t >> 6;
  float s = 0.f;
  for (int g = blockIdx.x * 4 + q; g < G; g += gridDim.x * 4)
    s += partials[(size_t)g * 64 + c];
  acc[q][c] = s;
  __syncthreads();
  if (t < 64)
    atomicAdd(&stats[t], acc[0][t] + acc[1][t] + acc[2][t] + acc[3][t]);
}

// ---------------- K4: normalize + affine + LeakyReLU ----------------
__global__ __launch_bounds__(256) void bn_apply_kernel(
    float* __restrict__ h, const float* __restrict__ stats,
    const float* __restrict__ gamma, const float* __restrict__ beta,
    int total, float invN) {
  int t = blockIdx.x * blockDim.x + threadIdx.x;
  int i4 = t * 4;
  if (i4 >= total) return;
  float4 v = *(const float4*)(h + i4);
  float r[4] = {v.x, v.y, v.z, v.w};
  int o0 = i4 & 31;
#pragma unroll
  for (int j = 0; j < 4; ++j) {
    int o = o0 + j;
    float m = stats[o] * invN;
    float var = fmaf(-m, m, stats[32 + o] * invN);
    float sc = rsqrtf(var + BN_EPS) * gamma[o];
    float val = (r[j] - m) * sc + beta[o];
    r[j] = val >= 0.f ? val : SLOPE * val;
  }
  *(float4*)(h + i4) = make_float4(r[0], r[1], r[2], r[3]);
}

// ---------------- Fallback path (tiny ws) ----------------
__global__ __launch_bounds__(256) void node_root_kernel(
    const float* __restrict__ x, const float* __restrict__ root,
    const float* __restrict__ bias, float* __restrict__ agg, int N) {
  __shared__ float rl[IN_F * OUT_F];
  __shared__ float bl[OUT_F];
  for (int t = threadIdx.x; t < IN_F * OUT_F; t += blockDim.x) rl[t] = root[t];
  if (threadIdx.x < OUT_F) bl[threadIdx.x] = bias[threadIdx.x];
  __syncthreads();
  int n = blockIdx.x * blockDim.x + threadIdx.x;
  bool valid = (n < N);
  int nu = valid ? n : 0;
  float xr[IN_F];
  const float4* xp = (const float4*)(x + (size_t)nu * IN_F);
#pragma unroll
  for (int q = 0; q < IN_F / 4; ++q) {
    float4 v = xp[q];
    xr[q * 4 + 0] = v.x; xr[q * 4 + 1] = v.y; xr[q * 4 + 2] = v.z; xr[q * 4 + 3] = v.w;
  }
  float acc[OUT_F];
#pragma unroll
  for (int o = 0; o < OUT_F; ++o) acc[o] = bl[o];
#pragma unroll
  for (int i = 0; i < IN_F; ++i) {
    float xi = xr[i];
#pragma unroll
    for (int o = 0; o < OUT_F; ++o) acc[o] = fmaf(xi, rl[i * OUT_F + o], acc[o]);
  }
  if (valid) {
    float4* op = (float4*)(agg + (size_t)n * OUT_F);
#pragma unroll
    for (int q = 0; q < OUT_F / 4; ++q)
      op[q] = make_float4(acc[q * 4 + 0], acc[q * 4 + 1], acc[q * 4 + 2], acc[q * 4 + 3]);
  }
}

__global__ __launch_bounds__(256) void edge_kernel(
    const float* __restrict__ x, const float* __restrict__ ef,
    const float* __restrict__ W, const float* __restrict__ b,
    const int* __restrict__ ei, float* __restrict__ agg, int E) {
  __shared__ float Wl[EDGE_F * IN_F * OUT_F];
  int e = blockIdx.x * blockDim.x + threadIdx.x;
  bool valid = (e < E);
  int eu = valid ? e : 0;
  int s = ei[eu];
  int d = ei[E + eu];
  float efr[EDGE_F];
  {
    const float4* ep = (const float4*)(ef + (size_t)eu * EDGE_F);
#pragma unroll
    for (int q = 0; q < EDGE_F / 4; ++q) {
      float4 v = ep[q];
      efr[q * 4 + 0] = v.x; efr[q * 4 + 1] = v.y;
      efr[q * 4 + 2] = v.z; efr[q * 4 + 3] = v.w;
    }
  }
  const float* xrow = x + (size_t)s * IN_F;
  float acc[OUT_F];
#pragma unroll
  for (int o = 0; o < OUT_F; ++o) acc[o] = 0.f;
  for (int t = threadIdx.x; t < IN_F * OUT_F; t += 256) Wl[t] = b[t];
  __syncthreads();
  for (int i = 0; i < IN_F; ++i) {
    float xi = xrow[i];
    const float* br = &Wl[i * OUT_F];
#pragma unroll
    for (int o = 0; o < OUT_F; ++o) acc[o] = fmaf(xi, br[o], acc[o]);
  }
  __syncthreads();
  for (int t = threadIdx.x; t < EDGE_F * IN_F * OUT_F / 4; t += 256)
    ((float4*)Wl)[t] = ((const float4*)W)[t];
  __syncthreads();
  for (int i = 0; i < IN_F; ++i) {
    float xi = xrow[i];
#pragma unroll
    for (int f = 0; f < EDGE_F; ++f) {
      float m = efr[f] * xi;
      const float* wr = &Wl[(f * IN_F + i) * OUT_F];
#pragma unroll
      for (int o = 0; o < OUT_F; ++o) acc[o] = fmaf(m, wr[o], acc[o]);
    }
  }
  if (valid) {
    float* dp = agg + (size_t)d * OUT_F;
#pragma unroll
    for (int o = 0; o < OUT_F; ++o) atomicAdd(dp + o, acc[o]);
  }
}

__global__ __launch_bounds__(256) void bn_stats_kernel(
    const float* __restrict__ h, float* __restrict__ stats, int total) {
  int t = blockIdx.x * blockDim.x + threadIdx.x;
  int stride = gridDim.x * blockDim.x;
  float s = 0.f, s2 = 0.f;
  for (int idx = t; idx < total; idx += stride) {
    float v = h[idx];
    s += v;
    s2 = fmaf(v, v, s2);
  }
  __shared__ float ls[256], ls2[256];
  ls[threadIdx.x] = s;
  ls2[threadIdx.x] = s2;
  __syncthreads();
  if (threadIdx.x < 32) {
    float a = ls[threadIdx.x], a2 = ls2[threadIdx.x];
    for (int j = 32 + threadIdx.x; j < 256; j += 32) { a += ls[j]; a2 += ls2[j]; }
    atomicAdd(&stats[threadIdx.x], a);
    atomicAdd(&stats[32 + threadIdx.x], a2);
  }
}

extern "C" void kernel_launch(void* const* d_in, const int* in_sizes, int n_in,
                              void* d_out, int out_size, void* d_ws, size_t ws_size,
                              hipStream_t stream) {
  const float* x     = (const float*)d_in[0];
  const float* ef    = (const float*)d_in[1];
  const float* W     = (const float*)d_in[2];
  const float* b     = (const float*)d_in[3];
  const float* root  = (const float*)d_in[4];
  const float* bias  = (const float*)d_in[5];
  const float* gamma = (const float*)d_in[6];
  const float* beta  = (const float*)d_in[7];
  const int*   ei    = (const int*)d_in[8];

  int N = in_sizes[0] / IN_F;
  int E = in_sizes[1] / EDGE_F;
  int total = N * OUT_F;
  int NB = (N + 31) / 32;
  int nb = (N + 255) / 256;

  float* out = (float*)d_out;
  char* wsb = (char*)d_ws;

  size_t off = 0;
  auto alloc = [&](size_t bytes) { size_t o = off; off = (off + bytes + 255) & ~(size_t)255; return o; };
  float*  stats    = (float*)(wsb + alloc(256));
  half_t* BtG      = (half_t*)(wsb + alloc((size_t)BCOLS * 32 * sizeof(half_t)));
  int*    cnt_s    = (int*)(wsb + alloc((size_t)NB * 4));
  int*    rp_s     = (int*)(wsb + alloc((size_t)(NB + 1) * 4));
  int*    cur_s    = (int*)(wsb + alloc((size_t)NB * 4));
  int*    cnt_d    = (int*)(wsb + alloc((size_t)N * 4));
  int*    rp_d     = (int*)(wsb + alloc((size_t)(N + 1) * 4));
  int*    cur_d    = (int*)(wsb + alloc((size_t)N * 4));
  int*    bsum     = (int*)(wsb + alloc((size_t)nb * 4));
  int*    bcur     = (int*)(wsb + alloc((size_t)nb * 4));
  int*    perm_s   = (int*)(wsb + alloc((size_t)E * 4));
  int*    perm_d   = (int*)(wsb + alloc((size_t)E * 4));
  float*  partials = (float*)(wsb + alloc((size_t)NB * 64 * sizeof(float)));
  half_t* msg      = (half_t*)(wsb + alloc((size_t)E * 32 * sizeof(half_t)));
  size_t need = off;

  bool fits = ((size_t)E << 5) < 0x7FFFFFFF;

  if (ws_size >= need && fits && nb <= 512) {
    int pgrid = (BCOLS * 32 + 255) / 256;
    int ngrid = (NB + 255) / 256;
    if (ngrid > pgrid) pgrid = ngrid;
    hipMemsetAsync(cnt_d, 0, (size_t)N * 4, stream);
    prep_bt_kernel<<<pgrid, 256, 0, stream>>>(W, b, BtG, cnt_s, stats, NB);
    hist2_kernel<<<(E + 255) / 256, 256, 0, stream>>>(ei, cnt_s, cnt_d, E);
    scan_s_kernel<<<1, 1024, 0, stream>>>(cnt_s, rp_s, cur_s, NB, E);
    scan_a_kernel<<<nb, 256, 0, stream>>>(cnt_d, rp_d, bsum, N);
    scan_b_kernel<<<1, 512, 0, stream>>>(bsum, bcur, nb);
    scan_c_kernel<<<nb, 256, 0, stream>>>(rp_d, cur_d, bcur, N, E);
    scatter2_kernel<<<(E + 255) / 256, 256, 0, stream>>>(ei, cur_s, cur_d, perm_s, perm_d, E);
    fused1_kernel<<<NB, 256, 0, stream>>>(x, BtG, ef, perm_s, rp_s, msg, N);
    agg2_kernel<<<NB, 256, 0, stream>>>(msg, perm_d, rp_d, x, root, bias, out, partials, N);
    stats_reduce_kernel<<<64, 256, 0, stream>>>(partials, stats, NB);
  } else {
    hipMemsetAsync(stats, 0, 256, stream);
    node_root_kernel<<<(N + 255) / 256, 256, 0, stream>>>(x, root, bias, out, N);
    edge_kernel<<<(E + 255) / 256, 256, 0, stream>>>(x, ef, W, b, ei, out, E);
    bn_stats_kernel<<<1024, 256, 0, stream>>>(out, stats, total);
  }
  bn_apply_kernel<<<(total / 4 + 255) / 256, 256, 0, stream>>>(out, stats, gamma, beta, total, 1.0f / (float)N);
}